// Round 3
// baseline (138.095 us; speedup 1.0000x reference)
//
#include <hip/hip_runtime.h>
#include <hip/hip_bf16.h>

typedef __bf16 bf16;
typedef bf16 bf16x8 __attribute__((ext_vector_type(8)));
typedef float f32x4 __attribute__((ext_vector_type(4)));
typedef float f32x16 __attribute__((ext_vector_type(16)));
typedef unsigned int u32;
typedef u32 u32x4 __attribute__((ext_vector_type(4)));
typedef int i32x2 __attribute__((ext_vector_type(2)));

// Problem constants
// x: [16][256][64][64] f32; w_qkv: [768][256]; b_qkv: [768]; pos: [1024][32]
// out: [16][256][32][32] f32  (= [b][h*32+d][n], n = hp*32+wp)

__device__ __forceinline__ u32 packbf2(float lo, float hi) {
    unsigned short a = __builtin_bit_cast(unsigned short, (bf16)lo);
    unsigned short b = __builtin_bit_cast(unsigned short, (bf16)hi);
    return (u32)a | ((u32)b << 16);
}

#if __has_builtin(__builtin_amdgcn_exp2f)
#define EXP2(x) __builtin_amdgcn_exp2f(x)
#else
#define EXP2(x) __expf((x)*0.69314718055994531f)
#endif

__device__ __forceinline__ i32x2 pl32swap(u32 a, u32 b) {
#if __has_builtin(__builtin_amdgcn_permlane32_swap)
    return __builtin_amdgcn_permlane32_swap((int)a, (int)b, false, false);
#else
    int lid = __builtin_amdgcn_mbcnt_hi(~0u, __builtin_amdgcn_mbcnt_lo(~0u, 0));
    u32 ax = (u32)__shfl_xor((int)a, 32);
    u32 bx = (u32)__shfl_xor((int)b, 32);
    i32x2 r;
    r.x = (int)(lid < 32 ? a : bx);
    r.y = (int)(lid < 32 ? ax : b);
    return r;
#endif
}

__device__ __forceinline__ f32x16 zero16() {
    f32x16 z;
#pragma unroll
    for (int i = 0; i < 16; ++i) z[i] = 0.f;
    return z;
}

// async global->LDS, 16B per lane; ldst must be the wave-uniform base
__device__ __forceinline__ void gload_lds16(const bf16* gsrc, bf16* ldst) {
    __builtin_amdgcn_global_load_lds(
        (const __attribute__((address_space(1))) void*)gsrc,
        (__attribute__((address_space(3))) void*)ldst, 16, 0, 0);
}

// ---------------------------------------------------------------------------
// K1: x f32 [b][c][p=4096]  ->  XT bf16 [b][p][c]   (64x64 LDS tile transpose)
__global__ __launch_bounds__(256) void k_transpose_x(const float* __restrict__ x,
                                                     bf16* __restrict__ xt) {
    __shared__ __align__(16) bf16 tile[64][72];
    int b = blockIdx.z, cb = blockIdx.y, pb = blockIdx.x;
    int c0 = cb * 64, p0 = pb * 64;
    int t = threadIdx.x;
    int pr = (t & 15) * 4;
    int cr = t >> 4;
    const float* xp = x + ((size_t)(b * 256 + c0)) * 4096 + p0;
    for (int pass = 0; pass < 4; ++pass) {
        int c = cr + pass * 16;
        float4 v = *reinterpret_cast<const float4*>(xp + (size_t)c * 4096 + pr);
        tile[pr + 0][c] = (bf16)v.x;
        tile[pr + 1][c] = (bf16)v.y;
        tile[pr + 2][c] = (bf16)v.z;
        tile[pr + 3][c] = (bf16)v.w;
    }
    __syncthreads();
    bf16* op = xt + ((size_t)(b * 4096 + p0)) * 256 + c0;
    int c8 = (t & 7) * 8;
    int prow = t >> 3;
    for (int pass = 0; pass < 2; ++pass) {
        int p = prow + pass * 32;
        *reinterpret_cast<bf16x8*>(op + (size_t)p * 256 + c8) =
            *reinterpret_cast<const bf16x8*>(&tile[p][c8]);
    }
}

// ---------------------------------------------------------------------------
// K2: w f32 [768][256] -> bf16 same layout
__global__ __launch_bounds__(256) void k_convert_w(const float* __restrict__ w,
                                                   bf16* __restrict__ wb) {
    int i = (blockIdx.x * 256 + threadIdx.x) * 8;
    float4 a = *reinterpret_cast<const float4*>(w + i);
    float4 b4 = *reinterpret_cast<const float4*>(w + i + 4);
    bf16x8 o;
    o[0] = (bf16)a.x;  o[1] = (bf16)a.y;  o[2] = (bf16)a.z;  o[3] = (bf16)a.w;
    o[4] = (bf16)b4.x; o[5] = (bf16)b4.y; o[6] = (bf16)b4.z; o[7] = (bf16)b4.w;
    *reinterpret_cast<bf16x8*>(wb + i) = o;
}

// ---------------------------------------------------------------------------
// K3: GEMM (W[768x256] @ X[256x4096]) + bias + 2x2 maxpool, writes Q/K/V
//     directly in attention layouts. 128x128 tile, BK=64, double-buffered
//     global_load_lds staging with XOR-swizzled chunks.
//     mt 0-1 -> Q [bh][n][d] (+pos, *log2e/sqrt32); mt 2-3 -> K [bh][n][d];
//     mt 4-5 -> V [bh][d][n].
__global__ __launch_bounds__(256) void k_gemm_pool(const bf16* __restrict__ xt,
                                                   const bf16* __restrict__ wb,
                                                   const float* __restrict__ bias,
                                                   const float* __restrict__ pos,
                                                   bf16* __restrict__ Qb,
                                                   bf16* __restrict__ Kb,
                                                   bf16* __restrict__ Vb) {
    __shared__ __align__(16) bf16 bt[2][128 * 64];
    int b = blockIdx.z, mt = blockIdx.y, nt = blockIdx.x;
    int m0 = mt * 128, p0 = nt * 128;
    int t = threadIdx.x;
    int w = t >> 6, lane = t & 63, g = lane >> 4, q = lane & 15;

    const bf16* xtp = xt + ((size_t)(b * 4096 + p0)) * 256;
    const bf16* wbase = wb + (size_t)(m0 + w * 32) * 256;
    int srow = t >> 3;   // staging row (pass adds *32)
    int scb = t & 7;     // staging physical chunk

    f32x4 acc[2][8];
#pragma unroll
    for (int fr = 0; fr < 2; ++fr)
#pragma unroll
        for (int fc = 0; fc < 8; ++fc) acc[fr][fc] = (f32x4){0.f, 0.f, 0.f, 0.f};

    // per-lane read-side swizzled chunk offset (elements) for ks=0; ks=1 is ^32
    int co0 = ((g ^ (q & 7)) << 3);

    bf16x8 aC[4], aN[4];

#define STAGE(KC, BB)                                                          \
    {                                                                          \
        _Pragma("unroll")                                                      \
        for (int pass = 0; pass < 4; ++pass) {                                 \
            int row = srow + pass * 32;                                        \
            const bf16* gs = xtp + (size_t)row * 256 + (KC) * 64 +             \
                             ((scb ^ (row & 7)) << 3);                         \
            gload_lds16(gs, &bt[BB][(w * 8 + pass * 32) * 64]);                \
        }                                                                      \
    }
#define LOADA(KC, DST)                                                         \
    {                                                                          \
        _Pragma("unroll")                                                      \
        for (int ks = 0; ks < 2; ++ks)                                         \
            _Pragma("unroll")                                                  \
            for (int fr = 0; fr < 2; ++fr)                                     \
                DST[ks * 2 + fr] = *reinterpret_cast<const bf16x8*>(           \
                    wbase + (size_t)(fr * 16 + q) * 256 + (KC) * 64 +          \
                    ks * 32 + g * 8);                                          \
    }

    STAGE(0, 0);
    LOADA(0, aC);
    __syncthreads();

    for (int kc = 0; kc < 4; ++kc) {
        int cur = kc & 1;
        if (kc < 3) {
            STAGE(kc + 1, cur ^ 1);
            LOADA(kc + 1, aN);
        }
#pragma unroll
        for (int ks = 0; ks < 2; ++ks) {
            int co = ks ? (co0 ^ 32) : co0;
#pragma unroll
            for (int fc = 0; fc < 8; ++fc) {
                bf16x8 bfv = *reinterpret_cast<const bf16x8*>(
                    &bt[cur][(fc * 16 + q) * 64 + co]);
                acc[0][fc] = __builtin_amdgcn_mfma_f32_16x16x32_bf16(aC[ks * 2 + 0], bfv, acc[0][fc], 0, 0, 0);
                acc[1][fc] = __builtin_amdgcn_mfma_f32_16x16x32_bf16(aC[ks * 2 + 1], bfv, acc[1][fc], 0, 0, 0);
            }
        }
        __syncthreads();
        if (kc < 3) {
#pragma unroll
            for (int i = 0; i < 4; ++i) aC[i] = aN[i];
        }
    }
#undef STAGE
#undef LOADA

    // epilogue: 2x2 maxpool (w-pair via shfl_xor(1), h-pair via fc/fc+4) + bias
    int sec = m0 >> 8;  // 0=Q, 1=K, 2=V (block-uniform)
    const float QSCALE = 0.2550406682649681f;  // log2(e)/sqrt(32)
#pragma unroll
    for (int fr = 0; fr < 2; ++fr) {
#pragma unroll
        for (int r = 0; r < 4; ++r) {
            int o = m0 + w * 32 + fr * 16 + g * 4 + r;
            int h = (o >> 5) & 7, d = o & 31;
            size_t bh = (size_t)(b * 8 + h) * 32768;
            float bsv = bias[o];
#pragma unroll
            for (int fc = 0; fc < 4; ++fc) {
                float vmax = fmaxf(acc[fr][fc][r], acc[fr][fc + 4][r]);
                vmax = fmaxf(vmax, __shfl_xor(vmax, 1));
                vmax += bsv;
                int n = nt * 32 + fc * 8 + (q >> 1);
                if ((lane & 1) == 0) {
                    if (sec == 0) {
                        float pv = pos[n * 32 + d];
                        Qb[bh + (size_t)n * 32 + d] = (bf16)((vmax + pv) * QSCALE);
                    } else if (sec == 1) {
                        Kb[bh + (size_t)n * 32 + d] = (bf16)vmax;
                    } else {
                        Vb[bh + (size_t)d * 1024 + n] = (bf16)vmax;
                    }
                }
            }
        }
    }
}

// ---------------------------------------------------------------------------
// K5: attention, 32x32 MFMA, zero LDS/DS ops (unchanged from round 2 except
// V base). S^T = mfma(K,Q^T); p=exp2(s); P redistribution via permlane32_swap;
// O^T = mfma(V^T, P^T).
__global__ __launch_bounds__(256) void k_attn(const bf16* __restrict__ Q,
                                              const bf16* __restrict__ K,
                                              const bf16* __restrict__ V,
                                              float* __restrict__ out) {
    int qb = blockIdx.x, h = blockIdx.y, b = blockIdx.z;
    int t = threadIdx.x, w = t >> 6, lane = t & 63;
    int lq = lane & 31, hi = lane >> 5, hi8 = hi * 8;
    size_t bh = (size_t)b * 8 + h;
    const bf16* Qp = Q + bh * 32768;
    const bf16* Kp = K + bh * 32768;
    const bf16* Vp = V + bh * 32768;  // V^T [d][n]
    float* Op = out + ((size_t)(b * 256 + h * 32)) * 1024;
    int q0 = qb * 128 + w * 32;

    bf16x8 qf0 = *reinterpret_cast<const bf16x8*>(Qp + (size_t)(q0 + lq) * 32 + hi8);
    bf16x8 qf1 = *reinterpret_cast<const bf16x8*>(Qp + (size_t)(q0 + lq) * 32 + 16 + hi8);

    const bf16* kaddr = Kp + (size_t)lq * 32 + hi8;
    const bf16* vaddr = Vp + (size_t)lq * 1024 + hi8;

    f32x16 o = zero16();
    float run_s = 0.f;

    bf16x8 k0c = *reinterpret_cast<const bf16x8*>(kaddr);
    bf16x8 k1c = *reinterpret_cast<const bf16x8*>(kaddr + 16);
    bf16x8 v0c = *reinterpret_cast<const bf16x8*>(vaddr);
    bf16x8 v1c = *reinterpret_cast<const bf16x8*>(vaddr + 16);

    for (int kk = 0; kk < 32; ++kk) {
        int key0n = ((kk + 1) & 31) * 32;
        bf16x8 k0n = *reinterpret_cast<const bf16x8*>(kaddr + (size_t)key0n * 32);
        bf16x8 k1n = *reinterpret_cast<const bf16x8*>(kaddr + (size_t)key0n * 32 + 16);
        bf16x8 v0n = *reinterpret_cast<const bf16x8*>(vaddr + key0n);
        bf16x8 v1n = *reinterpret_cast<const bf16x8*>(vaddr + key0n + 16);

        f32x16 s = __builtin_amdgcn_mfma_f32_32x32x16_bf16(k0c, qf0, zero16(), 0, 0, 0);
        s = __builtin_amdgcn_mfma_f32_32x32x16_bf16(k1c, qf1, s, 0, 0, 0);

        float p[16];
#pragma unroll
        for (int r = 0; r < 16; ++r) p[r] = EXP2(s[r]);
        float ts = (((p[0] + p[1]) + (p[2] + p[3])) + ((p[4] + p[5]) + (p[6] + p[7]))) +
                   (((p[8] + p[9]) + (p[10] + p[11])) + ((p[12] + p[13]) + (p[14] + p[15])));
        run_s += ts;

        u32 pk0 = packbf2(p[0], p[1]),   pk1 = packbf2(p[2], p[3]);
        u32 pk2 = packbf2(p[4], p[5]),   pk3 = packbf2(p[6], p[7]);
        u32 pk4 = packbf2(p[8], p[9]),   pk5 = packbf2(p[10], p[11]);
        u32 pk6 = packbf2(p[12], p[13]), pk7 = packbf2(p[14], p[15]);

        i32x2 r02 = pl32swap(pk0, pk2);
        i32x2 r13 = pl32swap(pk1, pk3);
        i32x2 r46 = pl32swap(pk4, pk6);
        i32x2 r57 = pl32swap(pk5, pk7);

        u32x4 b0v = {(u32)r02.x, (u32)r13.x, (u32)r02.y, (u32)r13.y};
        u32x4 b1v = {(u32)r46.x, (u32)r57.x, (u32)r46.y, (u32)r57.y};
        bf16x8 pb0 = __builtin_bit_cast(bf16x8, b0v);
        bf16x8 pb1 = __builtin_bit_cast(bf16x8, b1v);

        o = __builtin_amdgcn_mfma_f32_32x32x16_bf16(v0c, pb0, o, 0, 0, 0);
        o = __builtin_amdgcn_mfma_f32_32x32x16_bf16(v1c, pb1, o, 0, 0, 0);

        k0c = k0n; k1c = k1n; v0c = v0n; v1c = v1n;
    }

    i32x2 rs = pl32swap(__builtin_bit_cast(u32, run_s), __builtin_bit_cast(u32, run_s));
    float tot = __builtin_bit_cast(float, (u32)rs.x) + __builtin_bit_cast(float, (u32)rs.y);
    float inv = 1.0f / tot;

#pragma unroll
    for (int r = 0; r < 16; ++r) {
        int dd = (r & 3) + 8 * (r >> 2) + 4 * hi;
        Op[(size_t)dd * 1024 + q0 + lq] = o[r] * inv;
    }
}

// ---------------------------------------------------------------------------
extern "C" void kernel_launch(void* const* d_in, const int* in_sizes, int n_in,
                              void* d_out, int out_size, void* d_ws, size_t ws_size,
                              hipStream_t stream) {
    const float* x = (const float*)d_in[0];
    const float* w = (const float*)d_in[1];
    const float* bias = (const float*)d_in[2];
    const float* pos = (const float*)d_in[3];
    float* outp = (float*)d_out;

    char* ws = (char*)d_ws;
    bf16* xt = (bf16*)(ws);               // 33,554,432
    bf16* wb = (bf16*)(ws + 33554432);    //    393,216
    bf16* Qb = (bf16*)(ws + 33947648);    //  8,388,608
    bf16* Kb = (bf16*)(ws + 42336256);    //  8,388,608
    bf16* Vb = (bf16*)(ws + 50724864);    //  8,388,608

    k_transpose_x<<<dim3(64, 4, 16), 256, 0, stream>>>(x, xt);
    k_convert_w<<<dim3(96), 256, 0, stream>>>(w, wb);
    k_gemm_pool<<<dim3(32, 6, 16), 256, 0, stream>>>(xt, wb, bias, pos, Qb, Kb, Vb);
    k_attn<<<dim3(8, 8, 16), 256, 0, stream>>>(Qb, Kb, Vb, outp);
}

// Round 5
// 133.280 us; speedup vs baseline: 1.0361x; 1.0361x over previous
//
#include <hip/hip_runtime.h>
#include <hip/hip_bf16.h>

typedef __bf16 bf16;
typedef bf16 bf16x8 __attribute__((ext_vector_type(8)));
typedef float f32x4 __attribute__((ext_vector_type(4)));
typedef float f32x16 __attribute__((ext_vector_type(16)));
typedef unsigned int u32;
typedef u32 u32x4 __attribute__((ext_vector_type(4)));
typedef int i32x2 __attribute__((ext_vector_type(2)));

// Problem constants
// x: [16][256][64][64] f32; w_qkv: [768][256]; b_qkv: [768]; pos: [1024][32]
// out: [16][256][32][32] f32  (= [b][h*32+d][n], n = hp*32+wp)

__device__ __forceinline__ u32 packbf2(float lo, float hi) {
    unsigned short a = __builtin_bit_cast(unsigned short, (bf16)lo);
    unsigned short b = __builtin_bit_cast(unsigned short, (bf16)hi);
    return (u32)a | ((u32)b << 16);
}

#if __has_builtin(__builtin_amdgcn_exp2f)
#define EXP2(x) __builtin_amdgcn_exp2f(x)
#else
#define EXP2(x) __expf((x)*0.69314718055994531f)
#endif

__device__ __forceinline__ i32x2 pl32swap(u32 a, u32 b) {
#if __has_builtin(__builtin_amdgcn_permlane32_swap)
    return __builtin_amdgcn_permlane32_swap((int)a, (int)b, false, false);
#else
    int lid = __builtin_amdgcn_mbcnt_hi(~0u, __builtin_amdgcn_mbcnt_lo(~0u, 0));
    u32 ax = (u32)__shfl_xor((int)a, 32);
    u32 bx = (u32)__shfl_xor((int)b, 32);
    i32x2 r;
    r.x = (int)(lid < 32 ? a : bx);
    r.y = (int)(lid < 32 ? ax : b);
    return r;
#endif
}

__device__ __forceinline__ f32x16 zero16() {
    f32x16 z;
#pragma unroll
    for (int i = 0; i < 16; ++i) z[i] = 0.f;
    return z;
}

// async global->LDS, 16B per lane; ldst must be the wave-uniform base
__device__ __forceinline__ void gload_lds16(const bf16* gsrc, bf16* ldst) {
    __builtin_amdgcn_global_load_lds(
        (const __attribute__((address_space(1))) void*)gsrc,
        (__attribute__((address_space(3))) void*)ldst, 16, 0, 0);
}

// pin memory-op program order at IR level and scheduler level
#define MEMFENCE()                               \
    do {                                         \
        asm volatile("" ::: "memory");           \
        __builtin_amdgcn_sched_barrier(0);       \
    } while (0)

#define WAITV(N)                                                   \
    do {                                                           \
        asm volatile("s_waitcnt vmcnt(" #N ")" ::: "memory");      \
        __builtin_amdgcn_sched_barrier(0);                         \
    } while (0)

#define WAITLGKM()                                                 \
    do {                                                           \
        asm volatile("s_waitcnt lgkmcnt(0)" ::: "memory");         \
        __builtin_amdgcn_sched_barrier(0);                         \
    } while (0)

// ---------------------------------------------------------------------------
// K1: x f32 [b][c][p=4096]  ->  XT bf16 [b][p][c]   (64x64 LDS tile transpose)
__global__ __launch_bounds__(256) void k_transpose_x(const float* __restrict__ x,
                                                     bf16* __restrict__ xt) {
    __shared__ __align__(16) bf16 tile[64][72];
    int b = blockIdx.z, cb = blockIdx.y, pb = blockIdx.x;
    int c0 = cb * 64, p0 = pb * 64;
    int t = threadIdx.x;
    int pr = (t & 15) * 4;
    int cr = t >> 4;
    const float* xp = x + ((size_t)(b * 256 + c0)) * 4096 + p0;
    for (int pass = 0; pass < 4; ++pass) {
        int c = cr + pass * 16;
        float4 v = *reinterpret_cast<const float4*>(xp + (size_t)c * 4096 + pr);
        tile[pr + 0][c] = (bf16)v.x;
        tile[pr + 1][c] = (bf16)v.y;
        tile[pr + 2][c] = (bf16)v.z;
        tile[pr + 3][c] = (bf16)v.w;
    }
    __syncthreads();
    bf16* op = xt + ((size_t)(b * 4096 + p0)) * 256 + c0;
    int c8 = (t & 7) * 8;
    int prow = t >> 3;
    for (int pass = 0; pass < 2; ++pass) {
        int p = prow + pass * 32;
        *reinterpret_cast<bf16x8*>(op + (size_t)p * 256 + c8) =
            *reinterpret_cast<const bf16x8*>(&tile[p][c8]);
    }
}

// ---------------------------------------------------------------------------
// K2: w f32 [768][256] -> bf16 same layout
__global__ __launch_bounds__(256) void k_convert_w(const float* __restrict__ w,
                                                   bf16* __restrict__ wb) {
    int i = (blockIdx.x * 256 + threadIdx.x) * 8;
    float4 a = *reinterpret_cast<const float4*>(w + i);
    float4 b4 = *reinterpret_cast<const float4*>(w + i + 4);
    bf16x8 o;
    o[0] = (bf16)a.x;  o[1] = (bf16)a.y;  o[2] = (bf16)a.z;  o[3] = (bf16)a.w;
    o[4] = (bf16)b4.x; o[5] = (bf16)b4.y; o[6] = (bf16)b4.z; o[7] = (bf16)b4.w;
    *reinterpret_cast<bf16x8*>(wb + i) = o;
}

// ---------------------------------------------------------------------------
// K3: GEMM (W[768x256] @ X[256x4096]) + bias + 2x2 maxpool, Q/K/V fused out.
//     All-upfront staging (3 LDS bufs + buf0 reuse), counted vmcnt waits,
//     all W A-frags preloaded. Per-wave VMEM queue: [A(16), S0(4), S1(4),
//     S2(4)]; retiring A+S0 => vmcnt<=8 (r4 bug: used 12 -> race).
__global__ __launch_bounds__(256) void k_gemm_pool(const bf16* __restrict__ xt,
                                                   const bf16* __restrict__ wb,
                                                   const float* __restrict__ bias,
                                                   const float* __restrict__ pos,
                                                   bf16* __restrict__ Qb,
                                                   bf16* __restrict__ Kb,
                                                   bf16* __restrict__ Vb) {
    __shared__ __align__(16) bf16 bt[3][128 * 64];   // 48 KB
    int b = blockIdx.z, mt = blockIdx.y, nt = blockIdx.x;
    int m0 = mt * 128, p0 = nt * 128;
    int t = threadIdx.x;
    int w = t >> 6, lane = t & 63, g = lane >> 4, q = lane & 15;

    const bf16* xtp = xt + ((size_t)(b * 4096 + p0)) * 256;
    const bf16* wbase = wb + (size_t)(m0 + w * 32) * 256;
    int srow = t >> 3;   // staging row (pass adds *32)
    int scb = t & 7;     // staging physical chunk
    int co0 = ((g ^ (q & 7)) << 3);  // read-side swizzled chunk offset, ks=0

#define STAGE(KC, BUF)                                                         \
    {                                                                          \
        _Pragma("unroll")                                                      \
        for (int pass = 0; pass < 4; ++pass) {                                 \
            int row = srow + pass * 32;                                        \
            const bf16* gs = xtp + (size_t)row * 256 + (KC) * 64 +             \
                             ((scb ^ (row & 7)) << 3);                         \
            gload_lds16(gs, (BUF) + (w * 8 + pass * 32) * 64);                 \
        }                                                                      \
    }

    // ---- preload ALL W A-frags (16 x 16B; L2-hot) ----
    bf16x8 A[16];  // A[kc*4 + ks*2 + fr]
#pragma unroll
    for (int kc = 0; kc < 4; ++kc)
#pragma unroll
        for (int ks = 0; ks < 2; ++ks)
#pragma unroll
            for (int fr = 0; fr < 2; ++fr)
                A[kc * 4 + ks * 2 + fr] = *reinterpret_cast<const bf16x8*>(
                    wbase + (size_t)(fr * 16 + q) * 256 + kc * 64 + ks * 32 + g * 8);
    MEMFENCE();
    STAGE(0, bt[0]);
    MEMFENCE();
    STAGE(1, bt[1]);
    MEMFENCE();
    STAGE(2, bt[2]);
    MEMFENCE();
    // per-thread VMEM queue now: [A(16), S0(4), S1(4), S2(4)] = 28

    f32x4 acc[2][8];
#pragma unroll
    for (int fr = 0; fr < 2; ++fr)
#pragma unroll
        for (int fc = 0; fc < 8; ++fc) acc[fr][fc] = (f32x4){0.f, 0.f, 0.f, 0.f};

#define COMPUTE(KC, BUF)                                                       \
    {                                                                          \
        _Pragma("unroll")                                                      \
        for (int ks = 0; ks < 2; ++ks) {                                       \
            int co = ks ? (co0 ^ 32) : co0;                                    \
            _Pragma("unroll")                                                  \
            for (int fc = 0; fc < 8; ++fc) {                                   \
                bf16x8 bfv = *reinterpret_cast<const bf16x8*>(                 \
                    &(BUF)[(fc * 16 + q) * 64 + co]);                          \
                acc[0][fc] = __builtin_amdgcn_mfma_f32_16x16x32_bf16(          \
                    A[(KC) * 4 + ks * 2 + 0], bfv, acc[0][fc], 0, 0, 0);       \
                acc[1][fc] = __builtin_amdgcn_mfma_f32_16x16x32_bf16(          \
                    A[(KC) * 4 + ks * 2 + 1], bfv, acc[1][fc], 0, 0, 0);       \
            }                                                                  \
        }                                                                      \
    }

    WAITV(8);                        // A(16)+S0(4) retired; S1,S2 in flight
    __builtin_amdgcn_s_barrier();
    __builtin_amdgcn_sched_barrier(0);
    COMPUTE(0, bt[0]);
    MEMFENCE();
    WAITV(4);                        // S1 retired (S2 may remain)
    __builtin_amdgcn_s_barrier();    // also: all waves done reading bt[0]
    __builtin_amdgcn_sched_barrier(0);
    STAGE(3, bt[0]);                 // kc3 data into buf0
    MEMFENCE();
    COMPUTE(1, bt[1]);
    MEMFENCE();
    WAITV(4);                        // S2 retired (S3 may remain)
    __builtin_amdgcn_s_barrier();
    __builtin_amdgcn_sched_barrier(0);
    COMPUTE(2, bt[2]);
    MEMFENCE();
    WAITV(0);                        // S3 retired
    __builtin_amdgcn_s_barrier();
    __builtin_amdgcn_sched_barrier(0);
    COMPUTE(3, bt[0]);
#undef STAGE
#undef COMPUTE

    // ---- epilogue: 2x2 maxpool + bias ----
    int sec = m0 >> 8;  // 0=Q, 1=K, 2=V (block-uniform)
    const int TP = 132;
    bf16* tile = bt[1];  // [32 n][132 o] staging for transposed Q/K stores
#pragma unroll
    for (int fr = 0; fr < 2; ++fr) {
#pragma unroll
        for (int r = 0; r < 4; ++r) {
            int o_l = w * 32 + fr * 16 + g * 4 + r;
            int o = m0 + o_l;
            float bsv = bias[o];
#pragma unroll
            for (int fc = 0; fc < 4; ++fc) {
                float vmax = fmaxf(acc[fr][fc][r], acc[fr][fc + 4][r]);
                vmax = fmaxf(vmax, __shfl_xor(vmax, 1));
                vmax += bsv;
                int n_l = fc * 8 + (q >> 1);
                if ((lane & 1) == 0) {
                    if (sec == 2) {
                        int d = o & 31;
                        size_t bh = (size_t)(b * 8 + ((o >> 5) & 7)) * 32768;
                        Vb[bh + (size_t)d * 1024 + (nt * 32 + n_l)] = (bf16)vmax;
                    } else {
                        tile[n_l * TP + o_l] = (bf16)vmax;
                    }
                }
            }
        }
    }

    if (sec < 2) {
        WAITLGKM();                  // ds_writes visible before barrier
        __builtin_amdgcn_s_barrier();
        __builtin_amdgcn_sched_barrier(0);
        const float QSCALE = 0.2550406682649681f;  // log2(e)/sqrt(32)
#pragma unroll
        for (int i = 0; i < 2; ++i) {
            int c = t * 2 + i;            // 512 chunks of 16B
            int n_l = c >> 4, ck = c & 15;
            int o_l = ck * 8;
            bf16x8 v = *reinterpret_cast<const bf16x8*>(&tile[n_l * TP + o_l]);
            int o = m0 + o_l;
            int h = (o >> 5) & 7, d0 = o & 31;
            int n = nt * 32 + n_l;
            size_t base = (size_t)(b * 8 + h) * 32768 + (size_t)n * 32 + d0;
            if (sec == 0) {
                float4 pv0 = *reinterpret_cast<const float4*>(pos + (size_t)n * 32 + d0);
                float4 pv1 = *reinterpret_cast<const float4*>(pos + (size_t)n * 32 + d0 + 4);
                bf16x8 ov;
                ov[0] = (bf16)(((float)v[0] + pv0.x) * QSCALE);
                ov[1] = (bf16)(((float)v[1] + pv0.y) * QSCALE);
                ov[2] = (bf16)(((float)v[2] + pv0.z) * QSCALE);
                ov[3] = (bf16)(((float)v[3] + pv0.w) * QSCALE);
                ov[4] = (bf16)(((float)v[4] + pv1.x) * QSCALE);
                ov[5] = (bf16)(((float)v[5] + pv1.y) * QSCALE);
                ov[6] = (bf16)(((float)v[6] + pv1.z) * QSCALE);
                ov[7] = (bf16)(((float)v[7] + pv1.w) * QSCALE);
                *reinterpret_cast<bf16x8*>(Qb + base) = ov;
            } else {
                *reinterpret_cast<bf16x8*>(Kb + base) = v;
            }
        }
    }
}

// ---------------------------------------------------------------------------
// K5: attention, 32x32 MFMA, zero LDS/DS ops. Grid (h, b, qb) so all blocks
// of one head land on one XCD (K/V 2MB/XCD -> L2-resident).
__global__ __launch_bounds__(256) void k_attn(const bf16* __restrict__ Q,
                                              const bf16* __restrict__ K,
                                              const bf16* __restrict__ V,
                                              float* __restrict__ out) {
    int h = blockIdx.x, b = blockIdx.y, qb = blockIdx.z;
    int t = threadIdx.x, w = t >> 6, lane = t & 63;
    int lq = lane & 31, hi = lane >> 5, hi8 = hi * 8;
    size_t bh = (size_t)b * 8 + h;
    const bf16* Qp = Q + bh * 32768;
    const bf16* Kp = K + bh * 32768;
    const bf16* Vp = V + bh * 32768;  // V^T [d][n]
    float* Op = out + ((size_t)(b * 256 + h * 32)) * 1024;
    int q0 = qb * 128 + w * 32;

    bf16x8 qf0 = *reinterpret_cast<const bf16x8*>(Qp + (size_t)(q0 + lq) * 32 + hi8);
    bf16x8 qf1 = *reinterpret_cast<const bf16x8*>(Qp + (size_t)(q0 + lq) * 32 + 16 + hi8);

    const bf16* kaddr = Kp + (size_t)lq * 32 + hi8;
    const bf16* vaddr = Vp + (size_t)lq * 1024 + hi8;

    f32x16 o = zero16();
    float run_s = 0.f;

    bf16x8 k0c = *reinterpret_cast<const bf16x8*>(kaddr);
    bf16x8 k1c = *reinterpret_cast<const bf16x8*>(kaddr + 16);
    bf16x8 v0c = *reinterpret_cast<const bf16x8*>(vaddr);
    bf16x8 v1c = *reinterpret_cast<const bf16x8*>(vaddr + 16);

    for (int kk = 0; kk < 32; ++kk) {
        int key0n = ((kk + 1) & 31) * 32;
        bf16x8 k0n = *reinterpret_cast<const bf16x8*>(kaddr + (size_t)key0n * 32);
        bf16x8 k1n = *reinterpret_cast<const bf16x8*>(kaddr + (size_t)key0n * 32 + 16);
        bf16x8 v0n = *reinterpret_cast<const bf16x8*>(vaddr + key0n);
        bf16x8 v1n = *reinterpret_cast<const bf16x8*>(vaddr + key0n + 16);

        f32x16 s = __builtin_amdgcn_mfma_f32_32x32x16_bf16(k0c, qf0, zero16(), 0, 0, 0);
        s = __builtin_amdgcn_mfma_f32_32x32x16_bf16(k1c, qf1, s, 0, 0, 0);

        float p[16];
#pragma unroll
        for (int r = 0; r < 16; ++r) p[r] = EXP2(s[r]);
        float ts = (((p[0] + p[1]) + (p[2] + p[3])) + ((p[4] + p[5]) + (p[6] + p[7]))) +
                   (((p[8] + p[9]) + (p[10] + p[11])) + ((p[12] + p[13]) + (p[14] + p[15])));
        run_s += ts;

        u32 pk0 = packbf2(p[0], p[1]),   pk1 = packbf2(p[2], p[3]);
        u32 pk2 = packbf2(p[4], p[5]),   pk3 = packbf2(p[6], p[7]);
        u32 pk4 = packbf2(p[8], p[9]),   pk5 = packbf2(p[10], p[11]);
        u32 pk6 = packbf2(p[12], p[13]), pk7 = packbf2(p[14], p[15]);

        i32x2 r02 = pl32swap(pk0, pk2);
        i32x2 r13 = pl32swap(pk1, pk3);
        i32x2 r46 = pl32swap(pk4, pk6);
        i32x2 r57 = pl32swap(pk5, pk7);

        u32x4 b0v = {(u32)r02.x, (u32)r13.x, (u32)r02.y, (u32)r13.y};
        u32x4 b1v = {(u32)r46.x, (u32)r57.x, (u32)r46.y, (u32)r57.y};
        bf16x8 pb0 = __builtin_bit_cast(bf16x8, b0v);
        bf16x8 pb1 = __builtin_bit_cast(bf16x8, b1v);

        o = __builtin_amdgcn_mfma_f32_32x32x16_bf16(v0c, pb0, o, 0, 0, 0);
        o = __builtin_amdgcn_mfma_f32_32x32x16_bf16(v1c, pb1, o, 0, 0, 0);

        k0c = k0n; k1c = k1n; v0c = v0n; v1c = v1n;
    }

    i32x2 rs = pl32swap(__builtin_bit_cast(u32, run_s), __builtin_bit_cast(u32, run_s));
    float tot = __builtin_bit_cast(float, (u32)rs.x) + __builtin_bit_cast(float, (u32)rs.y);
    float inv = 1.0f / tot;

#pragma unroll
    for (int r = 0; r < 16; ++r) {
        int dd = (r & 3) + 8 * (r >> 2) + 4 * hi;
        Op[(size_t)dd * 1024 + q0 + lq] = o[r] * inv;
    }
}

// ---------------------------------------------------------------------------
extern "C" void kernel_launch(void* const* d_in, const int* in_sizes, int n_in,
                              void* d_out, int out_size, void* d_ws, size_t ws_size,
                              hipStream_t stream) {
    const float* x = (const float*)d_in[0];
    const float* w = (const float*)d_in[1];
    const float* bias = (const float*)d_in[2];
    const float* pos = (const float*)d_in[3];
    float* outp = (float*)d_out;

    char* ws = (char*)d_ws;
    bf16* xt = (bf16*)(ws);               // 33,554,432
    bf16* wb = (bf16*)(ws + 33554432);    //    393,216
    bf16* Qb = (bf16*)(ws + 33947648);    //  8,388,608
    bf16* Kb = (bf16*)(ws + 42336256);    //  8,388,608
    bf16* Vb = (bf16*)(ws + 50724864);    //  8,388,608

    k_transpose_x<<<dim3(64, 4, 16), 256, 0, stream>>>(x, xt);
    k_convert_w<<<dim3(96), 256, 0, stream>>>(w, wb);
    k_gemm_pool<<<dim3(32, 6, 16), 256, 0, stream>>>(xt, wb, bias, pos, Qb, Kb, Vb);
    k_attn<<<dim3(8, 16, 8), 256, 0, stream>>>(Qb, Kb, Vb, outp);
}

// Round 6
// 127.309 us; speedup vs baseline: 1.0847x; 1.0469x over previous
//
#include <hip/hip_runtime.h>
#include <hip/hip_bf16.h>

typedef __bf16 bf16;
typedef bf16 bf16x8 __attribute__((ext_vector_type(8)));
typedef float f32x4 __attribute__((ext_vector_type(4)));
typedef float f32x16 __attribute__((ext_vector_type(16)));
typedef unsigned int u32;
typedef u32 u32x4 __attribute__((ext_vector_type(4)));
typedef int i32x2 __attribute__((ext_vector_type(2)));

// Problem constants
// x: [16][256][64][64] f32; w_qkv: [768][256]; b_qkv: [768]; pos: [1024][32]
// out: [16][256][32][32] f32  (= [b][h*32+d][n], n = hp*32+wp)

__device__ __forceinline__ u32 packbf2(float lo, float hi) {
    unsigned short a = __builtin_bit_cast(unsigned short, (bf16)lo);
    unsigned short b = __builtin_bit_cast(unsigned short, (bf16)hi);
    return (u32)a | ((u32)b << 16);
}

#if __has_builtin(__builtin_amdgcn_exp2f)
#define EXP2(x) __builtin_amdgcn_exp2f(x)
#else
#define EXP2(x) __expf((x)*0.69314718055994531f)
#endif

__device__ __forceinline__ i32x2 pl32swap(u32 a, u32 b) {
#if __has_builtin(__builtin_amdgcn_permlane32_swap)
    return __builtin_amdgcn_permlane32_swap((int)a, (int)b, false, false);
#else
    int lid = __builtin_amdgcn_mbcnt_hi(~0u, __builtin_amdgcn_mbcnt_lo(~0u, 0));
    u32 ax = (u32)__shfl_xor((int)a, 32);
    u32 bx = (u32)__shfl_xor((int)b, 32);
    i32x2 r;
    r.x = (int)(lid < 32 ? a : bx);
    r.y = (int)(lid < 32 ? ax : b);
    return r;
#endif
}

__device__ __forceinline__ f32x16 zero16() {
    f32x16 z;
#pragma unroll
    for (int i = 0; i < 16; ++i) z[i] = 0.f;
    return z;
}

// async global->LDS, 16B per lane; ldst must be the wave-uniform base
__device__ __forceinline__ void gload_lds16(const bf16* gsrc, bf16* ldst) {
    __builtin_amdgcn_global_load_lds(
        (const __attribute__((address_space(1))) void*)gsrc,
        (__attribute__((address_space(3))) void*)ldst, 16, 0, 0);
}

// pin memory-op program order at IR level and scheduler level
#define MEMFENCE()                               \
    do {                                         \
        asm volatile("" ::: "memory");           \
        __builtin_amdgcn_sched_barrier(0);       \
    } while (0)

#define WAITV(N)                                                   \
    do {                                                           \
        asm volatile("s_waitcnt vmcnt(" #N ")" ::: "memory");      \
        __builtin_amdgcn_sched_barrier(0);                         \
    } while (0)

#define WAITLGKM()                                                 \
    do {                                                           \
        asm volatile("s_waitcnt lgkmcnt(0)" ::: "memory");         \
        __builtin_amdgcn_sched_barrier(0);                         \
    } while (0)

// ---------------------------------------------------------------------------
// K1: x f32 [b][c][p=4096]  ->  XT bf16 [b][p][c]   (64x64 LDS tile transpose)
__global__ __launch_bounds__(256) void k_transpose_x(const float* __restrict__ x,
                                                     bf16* __restrict__ xt) {
    __shared__ __align__(16) bf16 tile[64][72];
    int b = blockIdx.z, cb = blockIdx.y, pb = blockIdx.x;
    int c0 = cb * 64, p0 = pb * 64;
    int t = threadIdx.x;
    int pr = (t & 15) * 4;
    int cr = t >> 4;
    const float* xp = x + ((size_t)(b * 256 + c0)) * 4096 + p0;
    for (int pass = 0; pass < 4; ++pass) {
        int c = cr + pass * 16;
        float4 v = *reinterpret_cast<const float4*>(xp + (size_t)c * 4096 + pr);
        tile[pr + 0][c] = (bf16)v.x;
        tile[pr + 1][c] = (bf16)v.y;
        tile[pr + 2][c] = (bf16)v.z;
        tile[pr + 3][c] = (bf16)v.w;
    }
    __syncthreads();
    bf16* op = xt + ((size_t)(b * 4096 + p0)) * 256 + c0;
    int c8 = (t & 7) * 8;
    int prow = t >> 3;
    for (int pass = 0; pass < 2; ++pass) {
        int p = prow + pass * 32;
        *reinterpret_cast<bf16x8*>(op + (size_t)p * 256 + c8) =
            *reinterpret_cast<const bf16x8*>(&tile[p][c8]);
    }
}

// ---------------------------------------------------------------------------
// K2: w f32 [768][256] -> bf16 same layout
__global__ __launch_bounds__(256) void k_convert_w(const float* __restrict__ w,
                                                   bf16* __restrict__ wb) {
    int i = (blockIdx.x * 256 + threadIdx.x) * 8;
    float4 a = *reinterpret_cast<const float4*>(w + i);
    float4 b4 = *reinterpret_cast<const float4*>(w + i + 4);
    bf16x8 o;
    o[0] = (bf16)a.x;  o[1] = (bf16)a.y;  o[2] = (bf16)a.z;  o[3] = (bf16)a.w;
    o[4] = (bf16)b4.x; o[5] = (bf16)b4.y; o[6] = (bf16)b4.z; o[7] = (bf16)b4.w;
    *reinterpret_cast<bf16x8*>(wb + i) = o;
}

// ---------------------------------------------------------------------------
// K3: GEMM (W[768x256] @ X[256x4096]) + bias + 2x2 maxpool, Q/K/V fused out.
//     Minimum-sync structure: BK = full 256, ONE 64KB LDS buffer, whole
//     X-tile staged in one 16-deep gload_lds burst, ONE barrier, then an
//     unbroken run of 128 MFMAs + swizzled ds_read_b128 (LDS read-only
//     after the barrier -> zero mid-loop syncs). A-frags reg-pipelined.
__global__ __launch_bounds__(256) void k_gemm_pool(const bf16* __restrict__ xt,
                                                   const bf16* __restrict__ wb,
                                                   const float* __restrict__ bias,
                                                   const float* __restrict__ pos,
                                                   bf16* __restrict__ Qb,
                                                   bf16* __restrict__ Kb,
                                                   bf16* __restrict__ Vb) {
    __shared__ __align__(16) bf16 bt[128 * 256];   // 64 KB, [p][c] rows 512B
    int b = blockIdx.z, mt = blockIdx.y, nt = blockIdx.x;
    int m0 = mt * 128, p0 = nt * 128;
    int t = threadIdx.x;
    int w = t >> 6, lane = t & 63, g = lane >> 4, q = lane & 15;

    const bf16* xtp = xt + ((size_t)(b * 4096 + p0)) * 256;
    const bf16* wbase = wb + (size_t)(m0 + w * 32) * 256;

    // ---- stage entire 128x256 X-tile; swizzled source, linear LDS dest ----
    // thread t, pass p: row = (t>>5) + p*8, chunk16B = (t&31) ^ (row&7) [low3]
    {
        int srow = t >> 5;           // 0..7 (wave-consistent: 2w + l>>5)
        int scb = t & 31;
        int wbase_row = (t >> 6) * 2;  // wave-uniform row base within pass
#pragma unroll
        for (int pass = 0; pass < 16; ++pass) {
            int row = srow + pass * 8;
            const bf16* gs = xtp + (size_t)row * 256 + ((scb ^ (row & 7)) << 3);
            gload_lds16(gs, bt + (pass * 8 + wbase_row) * 256);
        }
    }
    MEMFENCE();

    // ---- A-frags for kc=0 (W rows, L2-hot) ----
    bf16x8 Ac[4], An[4];
#define LOADA(KC, DST)                                                         \
    {                                                                          \
        _Pragma("unroll")                                                      \
        for (int ks = 0; ks < 2; ++ks)                                         \
            _Pragma("unroll")                                                  \
            for (int fr = 0; fr < 2; ++fr)                                     \
                DST[ks * 2 + fr] = *reinterpret_cast<const bf16x8*>(           \
                    wbase + (size_t)(fr * 16 + q) * 256 + (KC) * 64 +          \
                    ks * 32 + g * 8);                                          \
    }
    LOADA(0, Ac);
    MEMFENCE();

    f32x4 acc[2][8];
#pragma unroll
    for (int fr = 0; fr < 2; ++fr)
#pragma unroll
        for (int fc = 0; fc < 8; ++fc) acc[fr][fc] = (f32x4){0.f, 0.f, 0.f, 0.f};

    // queue per lane: [S(16), A0(4)] -> vmcnt(4) retires all staging
    WAITV(4);
    __builtin_amdgcn_s_barrier();
    __builtin_amdgcn_sched_barrier(0);

    // ---- unbroken MFMA run: 4 kc x 2 ks x 8 fc x 2 fr = 128 MFMAs ----
#pragma unroll
    for (int kc = 0; kc < 4; ++kc) {
        if (kc < 3) LOADA(kc + 1, An);
#pragma unroll
        for (int ks = 0; ks < 2; ++ks) {
#pragma unroll
            for (int fc = 0; fc < 8; ++fc) {
                int co = kc * 64 + (((ks * 4 + g) ^ (q & 7)) << 3);
                bf16x8 bfv = *reinterpret_cast<const bf16x8*>(
                    &bt[(fc * 16 + q) * 256 + co]);
                acc[0][fc] = __builtin_amdgcn_mfma_f32_16x16x32_bf16(
                    Ac[ks * 2 + 0], bfv, acc[0][fc], 0, 0, 0);
                acc[1][fc] = __builtin_amdgcn_mfma_f32_16x16x32_bf16(
                    Ac[ks * 2 + 1], bfv, acc[1][fc], 0, 0, 0);
            }
        }
        if (kc < 3) {
#pragma unroll
            for (int i = 0; i < 4; ++i) Ac[i] = An[i];
        }
    }
#undef LOADA

    // ---- all waves done reading bt; safe to reuse as epilogue tile ----
    __builtin_amdgcn_s_barrier();
    __builtin_amdgcn_sched_barrier(0);

    // ---- epilogue: 2x2 maxpool + bias ----
    int sec = m0 >> 8;  // 0=Q, 1=K, 2=V (block-uniform)
    const int TP = 132;
    bf16* tile = bt;    // [32 n][132 o] staging for transposed Q/K stores
#pragma unroll
    for (int fr = 0; fr < 2; ++fr) {
#pragma unroll
        for (int r = 0; r < 4; ++r) {
            int o_l = w * 32 + fr * 16 + g * 4 + r;
            int o = m0 + o_l;
            float bsv = bias[o];
#pragma unroll
            for (int fc = 0; fc < 4; ++fc) {
                float vmax = fmaxf(acc[fr][fc][r], acc[fr][fc + 4][r]);
                vmax = fmaxf(vmax, __shfl_xor(vmax, 1));
                vmax += bsv;
                int n_l = fc * 8 + (q >> 1);
                if ((lane & 1) == 0) {
                    if (sec == 2) {
                        int d = o & 31;
                        size_t bh = (size_t)(b * 8 + ((o >> 5) & 7)) * 32768;
                        Vb[bh + (size_t)d * 1024 + (nt * 32 + n_l)] = (bf16)vmax;
                    } else {
                        tile[n_l * TP + o_l] = (bf16)vmax;
                    }
                }
            }
        }
    }

    if (sec < 2) {
        WAITLGKM();                  // ds_writes visible before barrier
        __builtin_amdgcn_s_barrier();
        __builtin_amdgcn_sched_barrier(0);
        const float QSCALE = 0.2550406682649681f;  // log2(e)/sqrt(32)
#pragma unroll
        for (int i = 0; i < 2; ++i) {
            int c = t * 2 + i;            // 512 chunks of 16B
            int n_l = c >> 4, ck = c & 15;
            int o_l = ck * 8;
            bf16x8 v = *reinterpret_cast<const bf16x8*>(&tile[n_l * TP + o_l]);
            int o = m0 + o_l;
            int h = (o >> 5) & 7, d0 = o & 31;
            int n = nt * 32 + n_l;
            size_t base = (size_t)(b * 8 + h) * 32768 + (size_t)n * 32 + d0;
            if (sec == 0) {
                float4 pv0 = *reinterpret_cast<const float4*>(pos + (size_t)n * 32 + d0);
                float4 pv1 = *reinterpret_cast<const float4*>(pos + (size_t)n * 32 + d0 + 4);
                bf16x8 ov;
                ov[0] = (bf16)(((float)v[0] + pv0.x) * QSCALE);
                ov[1] = (bf16)(((float)v[1] + pv0.y) * QSCALE);
                ov[2] = (bf16)(((float)v[2] + pv0.z) * QSCALE);
                ov[3] = (bf16)(((float)v[3] + pv0.w) * QSCALE);
                ov[4] = (bf16)(((float)v[4] + pv1.x) * QSCALE);
                ov[5] = (bf16)(((float)v[5] + pv1.y) * QSCALE);
                ov[6] = (bf16)(((float)v[6] + pv1.z) * QSCALE);
                ov[7] = (bf16)(((float)v[7] + pv1.w) * QSCALE);
                *reinterpret_cast<bf16x8*>(Qb + base) = ov;
            } else {
                *reinterpret_cast<bf16x8*>(Kb + base) = v;
            }
        }
    }
}

// ---------------------------------------------------------------------------
// K5: attention, 32x32 MFMA, zero LDS/DS ops. Grid (h, b, qb) so all blocks
// of one head land on one XCD (K/V 2MB/XCD -> L2-resident).
__global__ __launch_bounds__(256) void k_attn(const bf16* __restrict__ Q,
                                              const bf16* __restrict__ K,
                                              const bf16* __restrict__ V,
                                              float* __restrict__ out) {
    int h = blockIdx.x, b = blockIdx.y, qb = blockIdx.z;
    int t = threadIdx.x, w = t >> 6, lane = t & 63;
    int lq = lane & 31, hi = lane >> 5, hi8 = hi * 8;
    size_t bh = (size_t)b * 8 + h;
    const bf16* Qp = Q + bh * 32768;
    const bf16* Kp = K + bh * 32768;
    const bf16* Vp = V + bh * 32768;  // V^T [d][n]
    float* Op = out + ((size_t)(b * 256 + h * 32)) * 1024;
    int q0 = qb * 128 + w * 32;

    bf16x8 qf0 = *reinterpret_cast<const bf16x8*>(Qp + (size_t)(q0 + lq) * 32 + hi8);
    bf16x8 qf1 = *reinterpret_cast<const bf16x8*>(Qp + (size_t)(q0 + lq) * 32 + 16 + hi8);

    const bf16* kaddr = Kp + (size_t)lq * 32 + hi8;
    const bf16* vaddr = Vp + (size_t)lq * 1024 + hi8;

    f32x16 o = zero16();
    float run_s = 0.f;

    bf16x8 k0c = *reinterpret_cast<const bf16x8*>(kaddr);
    bf16x8 k1c = *reinterpret_cast<const bf16x8*>(kaddr + 16);
    bf16x8 v0c = *reinterpret_cast<const bf16x8*>(vaddr);
    bf16x8 v1c = *reinterpret_cast<const bf16x8*>(vaddr + 16);

    for (int kk = 0; kk < 32; ++kk) {
        int key0n = ((kk + 1) & 31) * 32;
        bf16x8 k0n = *reinterpret_cast<const bf16x8*>(kaddr + (size_t)key0n * 32);
        bf16x8 k1n = *reinterpret_cast<const bf16x8*>(kaddr + (size_t)key0n * 32 + 16);
        bf16x8 v0n = *reinterpret_cast<const bf16x8*>(vaddr + key0n);
        bf16x8 v1n = *reinterpret_cast<const bf16x8*>(vaddr + key0n + 16);

        f32x16 s = __builtin_amdgcn_mfma_f32_32x32x16_bf16(k0c, qf0, zero16(), 0, 0, 0);
        s = __builtin_amdgcn_mfma_f32_32x32x16_bf16(k1c, qf1, s, 0, 0, 0);

        float p[16];
#pragma unroll
        for (int r = 0; r < 16; ++r) p[r] = EXP2(s[r]);
        float ts = (((p[0] + p[1]) + (p[2] + p[3])) + ((p[4] + p[5]) + (p[6] + p[7]))) +
                   (((p[8] + p[9]) + (p[10] + p[11])) + ((p[12] + p[13]) + (p[14] + p[15])));
        run_s += ts;

        u32 pk0 = packbf2(p[0], p[1]),   pk1 = packbf2(p[2], p[3]);
        u32 pk2 = packbf2(p[4], p[5]),   pk3 = packbf2(p[6], p[7]);
        u32 pk4 = packbf2(p[8], p[9]),   pk5 = packbf2(p[10], p[11]);
        u32 pk6 = packbf2(p[12], p[13]), pk7 = packbf2(p[14], p[15]);

        i32x2 r02 = pl32swap(pk0, pk2);
        i32x2 r13 = pl32swap(pk1, pk3);
        i32x2 r46 = pl32swap(pk4, pk6);
        i32x2 r57 = pl32swap(pk5, pk7);

        u32x4 b0v = {(u32)r02.x, (u32)r13.x, (u32)r02.y, (u32)r13.y};
        u32x4 b1v = {(u32)r46.x, (u32)r57.x, (u32)r46.y, (u32)r57.y};
        bf16x8 pb0 = __builtin_bit_cast(bf16x8, b0v);
        bf16x8 pb1 = __builtin_bit_cast(bf16x8, b1v);

        o = __builtin_amdgcn_mfma_f32_32x32x16_bf16(v0c, pb0, o, 0, 0, 0);
        o = __builtin_amdgcn_mfma_f32_32x32x16_bf16(v1c, pb1, o, 0, 0, 0);

        k0c = k0n; k1c = k1n; v0c = v0n; v1c = v1n;
    }

    i32x2 rs = pl32swap(__builtin_bit_cast(u32, run_s), __builtin_bit_cast(u32, run_s));
    float tot = __builtin_bit_cast(float, (u32)rs.x) + __builtin_bit_cast(float, (u32)rs.y);
    float inv = 1.0f / tot;

#pragma unroll
    for (int r = 0; r < 16; ++r) {
        int dd = (r & 3) + 8 * (r >> 2) + 4 * hi;
        Op[(size_t)dd * 1024 + q0 + lq] = o[r] * inv;
    }
}

// ---------------------------------------------------------------------------
extern "C" void kernel_launch(void* const* d_in, const int* in_sizes, int n_in,
                              void* d_out, int out_size, void* d_ws, size_t ws_size,
                              hipStream_t stream) {
    const float* x = (const float*)d_in[0];
    const float* w = (const float*)d_in[1];
    const float* bias = (const float*)d_in[2];
    const float* pos = (const float*)d_in[3];
    float* outp = (float*)d_out;

    char* ws = (char*)d_ws;
    bf16* xt = (bf16*)(ws);               // 33,554,432
    bf16* wb = (bf16*)(ws + 33554432);    //    393,216
    bf16* Qb = (bf16*)(ws + 33947648);    //  8,388,608
    bf16* Kb = (bf16*)(ws + 42336256);    //  8,388,608
    bf16* Vb = (bf16*)(ws + 50724864);    //  8,388,608

    k_transpose_x<<<dim3(64, 4, 16), 256, 0, stream>>>(x, xt);
    k_convert_w<<<dim3(96), 256, 0, stream>>>(w, wb);
    k_gemm_pool<<<dim3(32, 6, 16), 256, 0, stream>>>(xt, wb, bias, pos, Qb, Kb, Vb);
    k_attn<<<dim3(8, 16, 8), 256, 0, stream>>>(Qb, Kb, Vb, outp);
}

// Round 7
// 119.800 us; speedup vs baseline: 1.1527x; 1.0627x over previous
//
#include <hip/hip_runtime.h>
#include <hip/hip_bf16.h>

typedef __bf16 bf16;
typedef bf16 bf16x8 __attribute__((ext_vector_type(8)));
typedef float f32x4 __attribute__((ext_vector_type(4)));
typedef float f32x16 __attribute__((ext_vector_type(16)));
typedef unsigned int u32;
typedef u32 u32x4 __attribute__((ext_vector_type(4)));
typedef int i32x2 __attribute__((ext_vector_type(2)));

// Problem constants
// x: [16][256][64][64] f32; w_qkv: [768][256]; b_qkv: [768]; pos: [1024][32]
// out: [16][256][32][32] f32  (= [b][h*32+d][n], n = hp*32+wp)

__device__ __forceinline__ u32 packbf2(float lo, float hi) {
    unsigned short a = __builtin_bit_cast(unsigned short, (bf16)lo);
    unsigned short b = __builtin_bit_cast(unsigned short, (bf16)hi);
    return (u32)a | ((u32)b << 16);
}

#if __has_builtin(__builtin_amdgcn_exp2f)
#define EXP2(x) __builtin_amdgcn_exp2f(x)
#else
#define EXP2(x) __expf((x)*0.69314718055994531f)
#endif

__device__ __forceinline__ i32x2 pl32swap(u32 a, u32 b) {
#if __has_builtin(__builtin_amdgcn_permlane32_swap)
    return __builtin_amdgcn_permlane32_swap((int)a, (int)b, false, false);
#else
    int lid = __builtin_amdgcn_mbcnt_hi(~0u, __builtin_amdgcn_mbcnt_lo(~0u, 0));
    u32 ax = (u32)__shfl_xor((int)a, 32);
    u32 bx = (u32)__shfl_xor((int)b, 32);
    i32x2 r;
    r.x = (int)(lid < 32 ? a : bx);
    r.y = (int)(lid < 32 ? ax : b);
    return r;
#endif
}

__device__ __forceinline__ f32x16 zero16() {
    f32x16 z;
#pragma unroll
    for (int i = 0; i < 16; ++i) z[i] = 0.f;
    return z;
}

// async global->LDS, 16B per lane; ldst must be the wave-uniform base
__device__ __forceinline__ void gload_lds16(const bf16* gsrc, bf16* ldst) {
    __builtin_amdgcn_global_load_lds(
        (const __attribute__((address_space(1))) void*)gsrc,
        (__attribute__((address_space(3))) void*)ldst, 16, 0, 0);
}

// pin memory-op program order at IR level and scheduler level
#define MEMFENCE()                               \
    do {                                         \
        asm volatile("" ::: "memory");           \
        __builtin_amdgcn_sched_barrier(0);       \
    } while (0)

#define WAITV(N)                                                   \
    do {                                                           \
        asm volatile("s_waitcnt vmcnt(" #N ")" ::: "memory");      \
        __builtin_amdgcn_sched_barrier(0);                         \
    } while (0)

#define WAITLGKM()                                                 \
    do {                                                           \
        asm volatile("s_waitcnt lgkmcnt(0)" ::: "memory");         \
        __builtin_amdgcn_sched_barrier(0);                         \
    } while (0)

// ---------------------------------------------------------------------------
// K1: x f32 [b][c][p=4096]  ->  XT bf16 [b][p][c]   (64x64 LDS tile transpose)
__global__ __launch_bounds__(256) void k_transpose_x(const float* __restrict__ x,
                                                     bf16* __restrict__ xt) {
    __shared__ __align__(16) bf16 tile[64][72];
    int b = blockIdx.z, cb = blockIdx.y, pb = blockIdx.x;
    int c0 = cb * 64, p0 = pb * 64;
    int t = threadIdx.x;
    int pr = (t & 15) * 4;
    int cr = t >> 4;
    const float* xp = x + ((size_t)(b * 256 + c0)) * 4096 + p0;
    for (int pass = 0; pass < 4; ++pass) {
        int c = cr + pass * 16;
        float4 v = *reinterpret_cast<const float4*>(xp + (size_t)c * 4096 + pr);
        tile[pr + 0][c] = (bf16)v.x;
        tile[pr + 1][c] = (bf16)v.y;
        tile[pr + 2][c] = (bf16)v.z;
        tile[pr + 3][c] = (bf16)v.w;
    }
    __syncthreads();
    bf16* op = xt + ((size_t)(b * 4096 + p0)) * 256 + c0;
    int c8 = (t & 7) * 8;
    int prow = t >> 3;
    for (int pass = 0; pass < 2; ++pass) {
        int p = prow + pass * 32;
        *reinterpret_cast<bf16x8*>(op + (size_t)p * 256 + c8) =
            *reinterpret_cast<const bf16x8*>(&tile[p][c8]);
    }
}

// ---------------------------------------------------------------------------
// K2: w f32 [768][256] -> bf16 same layout
__global__ __launch_bounds__(256) void k_convert_w(const float* __restrict__ w,
                                                   bf16* __restrict__ wb) {
    int i = (blockIdx.x * 256 + threadIdx.x) * 8;
    float4 a = *reinterpret_cast<const float4*>(w + i);
    float4 b4 = *reinterpret_cast<const float4*>(w + i + 4);
    bf16x8 o;
    o[0] = (bf16)a.x;  o[1] = (bf16)a.y;  o[2] = (bf16)a.z;  o[3] = (bf16)a.w;
    o[4] = (bf16)b4.x; o[5] = (bf16)b4.y; o[6] = (bf16)b4.z; o[7] = (bf16)b4.w;
    *reinterpret_cast<bf16x8*>(wb + i) = o;
}

// ---------------------------------------------------------------------------
// K3: GEMM (W[768x256] @ X[256x4096]) + bias + 2x2 maxpool, Q/K/V fused out.
//     X-tile reuse structure: stage the 128p x 256c X-tile ONCE (one barrier),
//     then loop over all 6 W-panels (full M=768) with register-pipelined
//     A-frags -> 768 MFMAs/wave per staging event. Grid (nt=32, b=16) = 512
//     blocks = exactly 2/CU (LDS 72.4 KB). Per-panel epilogue: pool + bias;
//     Q/K transposed through a separate small LDS tile for coalesced stores.
__global__ __launch_bounds__(256) void k_gemm_pool(const bf16* __restrict__ xt,
                                                   const bf16* __restrict__ wb,
                                                   const float* __restrict__ bias,
                                                   const float* __restrict__ pos,
                                                   bf16* __restrict__ Qb,
                                                   bf16* __restrict__ Kb,
                                                   bf16* __restrict__ Vb) {
    __shared__ __align__(16) bf16 bt[128 * 256];   // 64 KB X-tile [p][c]
    __shared__ __align__(16) bf16 et[32 * 132];    // 8.4 KB epilogue transpose
    int b = blockIdx.y, nt = blockIdx.x;
    int p0 = nt * 128;
    int t = threadIdx.x;
    int w = t >> 6, lane = t & 63, g = lane >> 4, q = lane & 15;

    const bf16* xtp = xt + ((size_t)(b * 4096 + p0)) * 256;
    const bf16* wb_w = wb + (size_t)(w * 32) * 256;

    // ---- stage entire 128x256 X-tile; swizzled source, linear LDS dest ----
    {
        int srow = t >> 5;             // 0..7 (== w*2 + (lane>>5))
        int scb = t & 31;
        int wbase_row = w * 2;         // wave-uniform row base within pass
#pragma unroll
        for (int pass = 0; pass < 16; ++pass) {
            int row = srow + pass * 8;
            const bf16* gs = xtp + (size_t)row * 256 + ((scb ^ (row & 7)) << 3);
            gload_lds16(gs, bt + (pass * 8 + wbase_row) * 256);
        }
    }
    MEMFENCE();

    bf16x8 Ac[4], An[4];
#define LOADA(MT, KC, DST)                                                     \
    {                                                                          \
        _Pragma("unroll")                                                      \
        for (int ks = 0; ks < 2; ++ks)                                         \
            _Pragma("unroll")                                                  \
            for (int fr = 0; fr < 2; ++fr)                                     \
                DST[ks * 2 + fr] = *reinterpret_cast<const bf16x8*>(           \
                    wb_w + (size_t)((MT) * 128 + fr * 16 + q) * 256 +          \
                    (KC) * 64 + ks * 32 + g * 8);                              \
    }
    LOADA(0, 0, Ac);
    MEMFENCE();

    // queue per lane: [S(16), A0(4)] -> vmcnt(4) retires all staging
    WAITV(4);
    __builtin_amdgcn_s_barrier();
    __builtin_amdgcn_sched_barrier(0);

    const float QSCALE = 0.2550406682649681f;  // log2(e)/sqrt(32)
    const int TP = 132;

    for (int mt = 0; mt < 6; ++mt) {
        f32x4 acc[2][8];
#pragma unroll
        for (int fr = 0; fr < 2; ++fr)
#pragma unroll
            for (int fc = 0; fc < 8; ++fc) acc[fr][fc] = (f32x4){0.f, 0.f, 0.f, 0.f};

        // ---- 128 MFMAs (4 kc x 2 ks x 8 fc x 2 fr), bt read-only ----
#pragma unroll
        for (int kc = 0; kc < 4; ++kc) {
            if (kc < 3) {
                LOADA(mt, kc + 1, An);
            } else if (mt < 5) {
                LOADA(mt + 1, 0, An);
            }
#pragma unroll
            for (int ks = 0; ks < 2; ++ks) {
#pragma unroll
                for (int fc = 0; fc < 8; ++fc) {
                    int co = kc * 64 + (((ks * 4 + g) ^ (q & 7)) << 3);
                    bf16x8 bfv = *reinterpret_cast<const bf16x8*>(
                        &bt[(fc * 16 + q) * 256 + co]);
                    acc[0][fc] = __builtin_amdgcn_mfma_f32_16x16x32_bf16(
                        Ac[ks * 2 + 0], bfv, acc[0][fc], 0, 0, 0);
                    acc[1][fc] = __builtin_amdgcn_mfma_f32_16x16x32_bf16(
                        Ac[ks * 2 + 1], bfv, acc[1][fc], 0, 0, 0);
                }
            }
#pragma unroll
            for (int i = 0; i < 4; ++i) Ac[i] = An[i];
        }

        // ---- per-panel epilogue: 2x2 maxpool + bias ----
        int m0 = mt * 128;
        int sec = mt >> 1;  // 0=Q, 1=K, 2=V (block-uniform)
#pragma unroll
        for (int fr = 0; fr < 2; ++fr) {
#pragma unroll
            for (int r = 0; r < 4; ++r) {
                int o_l = w * 32 + fr * 16 + g * 4 + r;
                int o = m0 + o_l;
                float bsv = bias[o];
#pragma unroll
                for (int fc = 0; fc < 4; ++fc) {
                    float vmax = fmaxf(acc[fr][fc][r], acc[fr][fc + 4][r]);
                    vmax = fmaxf(vmax, __shfl_xor(vmax, 1));
                    vmax += bsv;
                    int n_l = fc * 8 + (q >> 1);
                    if ((lane & 1) == 0) {
                        if (sec == 2) {
                            int d = o & 31;
                            size_t bh = (size_t)(b * 8 + ((o >> 5) & 7)) * 32768;
                            Vb[bh + (size_t)d * 1024 + (nt * 32 + n_l)] = (bf16)vmax;
                        } else {
                            et[n_l * TP + o_l] = (bf16)vmax;
                        }
                    }
                }
            }
        }

        if (sec < 2) {
            WAITLGKM();                  // ds_writes visible before barrier
            __builtin_amdgcn_s_barrier();
            __builtin_amdgcn_sched_barrier(0);
#pragma unroll
            for (int i = 0; i < 2; ++i) {
                int c = t * 2 + i;            // 512 chunks of 16B
                int n_l = c >> 4, ck = c & 15;
                int o_l = ck * 8;
                bf16x8 v = *reinterpret_cast<const bf16x8*>(&et[n_l * TP + o_l]);
                int o = m0 + o_l;
                int h = (o >> 5) & 7, d0 = o & 31;
                int n = nt * 32 + n_l;
                size_t base = (size_t)(b * 8 + h) * 32768 + (size_t)n * 32 + d0;
                if (sec == 0) {
                    float4 pv0 = *reinterpret_cast<const float4*>(pos + (size_t)n * 32 + d0);
                    float4 pv1 = *reinterpret_cast<const float4*>(pos + (size_t)n * 32 + d0 + 4);
                    bf16x8 ov;
                    ov[0] = (bf16)(((float)v[0] + pv0.x) * QSCALE);
                    ov[1] = (bf16)(((float)v[1] + pv0.y) * QSCALE);
                    ov[2] = (bf16)(((float)v[2] + pv0.z) * QSCALE);
                    ov[3] = (bf16)(((float)v[3] + pv0.w) * QSCALE);
                    ov[4] = (bf16)(((float)v[4] + pv1.x) * QSCALE);
                    ov[5] = (bf16)(((float)v[5] + pv1.y) * QSCALE);
                    ov[6] = (bf16)(((float)v[6] + pv1.z) * QSCALE);
                    ov[7] = (bf16)(((float)v[7] + pv1.w) * QSCALE);
                    *reinterpret_cast<bf16x8*>(Qb + base) = ov;
                } else {
                    *reinterpret_cast<bf16x8*>(Kb + base) = v;
                }
            }
            __builtin_amdgcn_s_barrier();   // et reads done before next panel
            __builtin_amdgcn_sched_barrier(0);
        }
    }
#undef LOADA
}

// ---------------------------------------------------------------------------
// K5: attention, 32x32 MFMA, zero LDS/DS ops. Grid (h, b, qb) so all blocks
// of one head land on one XCD (K/V 2MB/XCD -> L2-resident).
__global__ __launch_bounds__(256) void k_attn(const bf16* __restrict__ Q,
                                              const bf16* __restrict__ K,
                                              const bf16* __restrict__ V,
                                              float* __restrict__ out) {
    int h = blockIdx.x, b = blockIdx.y, qb = blockIdx.z;
    int t = threadIdx.x, w = t >> 6, lane = t & 63;
    int lq = lane & 31, hi = lane >> 5, hi8 = hi * 8;
    size_t bh = (size_t)b * 8 + h;
    const bf16* Qp = Q + bh * 32768;
    const bf16* Kp = K + bh * 32768;
    const bf16* Vp = V + bh * 32768;  // V^T [d][n]
    float* Op = out + ((size_t)(b * 256 + h * 32)) * 1024;
    int q0 = qb * 128 + w * 32;

    bf16x8 qf0 = *reinterpret_cast<const bf16x8*>(Qp + (size_t)(q0 + lq) * 32 + hi8);
    bf16x8 qf1 = *reinterpret_cast<const bf16x8*>(Qp + (size_t)(q0 + lq) * 32 + 16 + hi8);

    const bf16* kaddr = Kp + (size_t)lq * 32 + hi8;
    const bf16* vaddr = Vp + (size_t)lq * 1024 + hi8;

    f32x16 o = zero16();
    float run_s = 0.f;

    bf16x8 k0c = *reinterpret_cast<const bf16x8*>(kaddr);
    bf16x8 k1c = *reinterpret_cast<const bf16x8*>(kaddr + 16);
    bf16x8 v0c = *reinterpret_cast<const bf16x8*>(vaddr);
    bf16x8 v1c = *reinterpret_cast<const bf16x8*>(vaddr + 16);

    for (int kk = 0; kk < 32; ++kk) {
        int key0n = ((kk + 1) & 31) * 32;
        bf16x8 k0n = *reinterpret_cast<const bf16x8*>(kaddr + (size_t)key0n * 32);
        bf16x8 k1n = *reinterpret_cast<const bf16x8*>(kaddr + (size_t)key0n * 32 + 16);
        bf16x8 v0n = *reinterpret_cast<const bf16x8*>(vaddr + key0n);
        bf16x8 v1n = *reinterpret_cast<const bf16x8*>(vaddr + key0n + 16);

        f32x16 s = __builtin_amdgcn_mfma_f32_32x32x16_bf16(k0c, qf0, zero16(), 0, 0, 0);
        s = __builtin_amdgcn_mfma_f32_32x32x16_bf16(k1c, qf1, s, 0, 0, 0);

        float p[16];
#pragma unroll
        for (int r = 0; r < 16; ++r) p[r] = EXP2(s[r]);
        float ts = (((p[0] + p[1]) + (p[2] + p[3])) + ((p[4] + p[5]) + (p[6] + p[7]))) +
                   (((p[8] + p[9]) + (p[10] + p[11])) + ((p[12] + p[13]) + (p[14] + p[15])));
        run_s += ts;

        u32 pk0 = packbf2(p[0], p[1]),   pk1 = packbf2(p[2], p[3]);
        u32 pk2 = packbf2(p[4], p[5]),   pk3 = packbf2(p[6], p[7]);
        u32 pk4 = packbf2(p[8], p[9]),   pk5 = packbf2(p[10], p[11]);
        u32 pk6 = packbf2(p[12], p[13]), pk7 = packbf2(p[14], p[15]);

        i32x2 r02 = pl32swap(pk0, pk2);
        i32x2 r13 = pl32swap(pk1, pk3);
        i32x2 r46 = pl32swap(pk4, pk6);
        i32x2 r57 = pl32swap(pk5, pk7);

        u32x4 b0v = {(u32)r02.x, (u32)r13.x, (u32)r02.y, (u32)r13.y};
        u32x4 b1v = {(u32)r46.x, (u32)r57.x, (u32)r46.y, (u32)r57.y};
        bf16x8 pb0 = __builtin_bit_cast(bf16x8, b0v);
        bf16x8 pb1 = __builtin_bit_cast(bf16x8, b1v);

        o = __builtin_amdgcn_mfma_f32_32x32x16_bf16(v0c, pb0, o, 0, 0, 0);
        o = __builtin_amdgcn_mfma_f32_32x32x16_bf16(v1c, pb1, o, 0, 0, 0);

        k0c = k0n; k1c = k1n; v0c = v0n; v1c = v1n;
    }

    i32x2 rs = pl32swap(__builtin_bit_cast(u32, run_s), __builtin_bit_cast(u32, run_s));
    float tot = __builtin_bit_cast(float, (u32)rs.x) + __builtin_bit_cast(float, (u32)rs.y);
    float inv = 1.0f / tot;

#pragma unroll
    for (int r = 0; r < 16; ++r) {
        int dd = (r & 3) + 8 * (r >> 2) + 4 * hi;
        Op[(size_t)dd * 1024 + q0 + lq] = o[r] * inv;
    }
}

// ---------------------------------------------------------------------------
extern "C" void kernel_launch(void* const* d_in, const int* in_sizes, int n_in,
                              void* d_out, int out_size, void* d_ws, size_t ws_size,
                              hipStream_t stream) {
    const float* x = (const float*)d_in[0];
    const float* w = (const float*)d_in[1];
    const float* bias = (const float*)d_in[2];
    const float* pos = (const float*)d_in[3];
    float* outp = (float*)d_out;

    char* ws = (char*)d_ws;
    bf16* xt = (bf16*)(ws);               // 33,554,432
    bf16* wb = (bf16*)(ws + 33554432);    //    393,216
    bf16* Qb = (bf16*)(ws + 33947648);    //  8,388,608
    bf16* Kb = (bf16*)(ws + 42336256);    //  8,388,608
    bf16* Vb = (bf16*)(ws + 50724864);    //  8,388,608

    k_transpose_x<<<dim3(64, 4, 16), 256, 0, stream>>>(x, xt);
    k_convert_w<<<dim3(96), 256, 0, stream>>>(w, wb);
    k_gemm_pool<<<dim3(32, 16), 256, 0, stream>>>(xt, wb, bias, pos, Qb, Kb, Vb);
    k_attn<<<dim3(8, 16, 8), 256, 0, stream>>>(Qb, Kb, Vb, outp);
}